// Round 16
// baseline (302.414 us; speedup 1.0000x reference)
//
#include <hip/hip_runtime.h>

#define BDIM 512
#define PACK_BDIM 256

typedef __attribute__((ext_vector_type(8))) short bf16x8;
typedef __attribute__((ext_vector_type(4))) float f32x4;
typedef __attribute__((ext_vector_type(4))) unsigned int u32x4;

__device__ __forceinline__ unsigned short f2b(float x) {   // round-to-nearest-even
    unsigned u = __float_as_uint(x);
    return (unsigned short)((u + 0x7fffu + ((u >> 16) & 1u)) >> 16);
}

typedef __attribute__((address_space(1))) const unsigned int ga_u32;
typedef __attribute__((address_space(3))) unsigned int la_u32;
__device__ __forceinline__ void gload_lds16(const void* g, void* l) {
    __builtin_amdgcn_global_load_lds((ga_u32*)g, (la_u32*)l, 16, 0, 0);
}

// Pack 9 fp32 128x128 weights into SINGLE round-to-nearest bf16 blocks
// (32 KB per gemm; 2-term split keeps only the A-side correction), plus all
// 9 biases (fp32) at the end. Per gemm g: chunk cf=c*8+f (1 KB), byte=lane*16:
// 8 bf16 for k=c*32+(lane>>4)*8+i, n=f*16+(lane&15).
// Bias floats at short-offset 147456 (byte 294912): biasf[g*128 + col].
__global__ __launch_bounds__(PACK_BDIM) void pack_weights(
    const float* __restrict__ w0, const float* __restrict__ w1,
    const float* __restrict__ w2, const float* __restrict__ w3,
    const float* __restrict__ w4, const float* __restrict__ w5,
    const float* __restrict__ w6, const float* __restrict__ w7,
    const float* __restrict__ w8,
    const float* __restrict__ b0, const float* __restrict__ b1,
    const float* __restrict__ b2, const float* __restrict__ b3,
    const float* __restrict__ b4, const float* __restrict__ b5,
    const float* __restrict__ b6, const float* __restrict__ b7,
    const float* __restrict__ b8, unsigned short* __restrict__ wp)
{
    __shared__ float wsm[16384];
    const float* W; const float* Bp;
    switch (blockIdx.x) {
        case 0: W = w0; Bp = b0; break; case 1: W = w1; Bp = b1; break;
        case 2: W = w2; Bp = b2; break; case 3: W = w3; Bp = b3; break;
        case 4: W = w4; Bp = b4; break; case 5: W = w5; Bp = b5; break;
        case 6: W = w6; Bp = b6; break; case 7: W = w7; Bp = b7; break;
        default: W = w8; Bp = b8; break;
    }
    const int tid = threadIdx.x;
    for (int i = tid; i < 16384; i += PACK_BDIM) wsm[i] = W[i];
    float* biasf = (float*)(wp + 147456);
    if (tid < 128) biasf[blockIdx.x * 128 + tid] = Bp[tid];
    __syncthreads();
    unsigned short* dst = wp + (size_t)blockIdx.x * 16384;
    for (int item = tid; item < 2048; item += PACK_BDIM) {
        const int lane = item & 63, cf = item >> 6;    // cf = c*8+f, 0..31
        const int c = cf >> 3, f = cf & 7;
        const int k0 = c * 32 + (lane >> 4) * 8;
        const int n  = f * 16 + (lane & 15);
        u32x4 vv;
        for (int i2 = 0; i2 < 4; i2++) {
            unsigned short lo = f2b(wsm[(k0 + 2 * i2)     * 128 + n]);
            unsigned short hi = f2b(wsm[(k0 + 2 * i2 + 1) * 128 + n]);
            vv[i2] = (unsigned)lo | ((unsigned)hi << 16);
        }
        *(u32x4*)(dst + (size_t)cf * 512 + lane * 8) = vv;
    }
}

// Fused dual-input GRU cell. grid = B/64, 512 thr = 8 waves = 4 rowgrp x
// 2 colgrp; per wave 16 rows x 64 cols -> 4-frag G (16 regs).
// R13/R15 diagnosis: 22 lockstep barriers x vmcnt drains = ~50% wall stall
// (all pipes <50% busy). R16: 2-TERM SPLIT — W stored RTN-bf16 single block
// (error = A*(W-rtn(W)) ~ 2^-9 RMS rel; A-side Al*Wh correction kept so A is
// exact to 2^-16). One 32KB stage + one compute phase per gemm:
// barriers 22 -> 12, staging traffic halved, MFMA -33%.
// Buffer schedule (cb): u0 b0, u1 b1, u2 b0, u3 b0(W)/b1(A=rh), u4 b1,
// u5 b0, u6 b1, u7 b0, u8 b1; prefetch one ahead except holes at u2/u8;
// rh transposes through buf1 (u2->u3), output through buf0 at the end.
// order u: 0 hr(6), 1 ir(0), 2 sr(3), 3 hn(8,LDS-A), 4 in(2), 5 sn(5),
//          6 hz(7), 7 iz(1), 8 sz(4).
__global__ __launch_bounds__(BDIM) __attribute__((amdgpu_waves_per_eu(4)))
void gru_fused(
    const float* __restrict__ inp, const float* __restrict__ seqp,
    const float* __restrict__ hid, const unsigned short* __restrict__ wp,
    float* __restrict__ outp)
{
    __shared__ __align__(16) unsigned short wbuf[2][16384]; // 2 x 32 KiB
    float* tbR = (float*)wbuf[1];   // rh transpose overlay (u2 -> u3)
    float* tbO = (float*)wbuf[0];   // output transpose overlay (epilogue)

    const int tid    = threadIdx.x;
    const int lane   = tid & 63;
    const int wid    = tid >> 6;       // 0..7
    const int rowgrp = wid >> 1;       // 0..3
    const int colgrp = wid & 1;        // 0..1
    const int agrp   = lane >> 4;      // 0..3
    const int a16    = lane & 15;
    const int ncol0  = colgrp * 64;
    const size_t row0 = (size_t)blockIdx.x * 64;
    const int locrow_a = rowgrp * 16 + a16;              // 0..63
    const int rswA = (locrow_a & 7) << 3;

    const float* pAin  = inp  + (row0 + locrow_a) * 128;
    const float* pAseq = seqp + (row0 + locrow_a) * 128;
    const float* pAhid = hid  + (row0 + locrow_a) * 128;
    const float* biasf = (const float*)(wp + 147456);

    f32x4 hx[4], s1[4], nacc[4], G[4];
    const f32x4 zv = {0.f, 0.f, 0.f, 0.f};

    auto stageu = [&](int g, int b) {   // issue 32KB stage, no wait
        const char* src = (const char*)wp + (size_t)g * 32768;
        char* dstb = (char*)wbuf[b];
        #pragma unroll
        for (int j = 0; j < 4; j++) {
            const int off = (j * 8 + wid) * 1024;  // wave-uniform LDS base
            gload_lds16(src + off + lane * 16, dstb + off);
        }
    };

    // Truncation split of A into ah (hi) + al (remainder): ah+al == A exactly
    // to fp32 rounding of the remainder (~2^-17 rel). perm(e1,e0,0x07060302)
    // packs the two bf16-hi halves in one instruction.
    auto splitc2 = [&](f32x4 x0, f32x4 x1, bf16x8& ah, bf16x8& al) {
        u32x4 a, l;
        #pragma unroll
        for (int p = 0; p < 2; p++) {
            unsigned e0 = __float_as_uint(x0[2 * p]);
            unsigned e1 = __float_as_uint(x0[2 * p + 1]);
            a[p] = __builtin_amdgcn_perm(e1, e0, 0x07060302u);
            float d0 = x0[2 * p]     - __uint_as_float(e0 & 0xffff0000u);
            float d1 = x0[2 * p + 1] - __uint_as_float(e1 & 0xffff0000u);
            l[p] = __builtin_amdgcn_perm(__float_as_uint(d1), __float_as_uint(d0), 0x07060302u);
            unsigned f0 = __float_as_uint(x1[2 * p]);
            unsigned f1 = __float_as_uint(x1[2 * p + 1]);
            a[2 + p] = __builtin_amdgcn_perm(f1, f0, 0x07060302u);
            float g0 = x1[2 * p]     - __uint_as_float(f0 & 0xffff0000u);
            float g1 = x1[2 * p + 1] - __uint_as_float(f1 & 0xffff0000u);
            l[2 + p] = __builtin_amdgcn_perm(__float_as_uint(g1), __float_as_uint(g0), 0x07060302u);
        }
        ah = *(const bf16x8*)&a;
        al = *(const bf16x8*)&l;
    };

    // G = (Ah+Al) @ W + bias  (A from global, W = RTN bf16 from wbuf[b])
    auto gemmG = [&](int b, const float* pA, int g) {
        #pragma unroll
        for (int f = 0; f < 4; f++) G[f] = zv;
        const unsigned short* wb = wbuf[b];
        #pragma unroll
        for (int c = 0; c < 4; c++) {
            const float* p = pA + c * 32 + agrp * 8;
            bf16x8 ah, al;
            splitc2(*(const f32x4*)(p), *(const f32x4*)(p + 4), ah, al);
            __builtin_amdgcn_s_setprio(1);
            #pragma unroll
            for (int f = 0; f < 4; f++) {
                const int fglob = colgrp * 4 + f;
                const bf16x8 w = *(const bf16x8*)(&wb[(size_t)(c * 8 + fglob) * 512 + lane * 8]);
                G[f] = __builtin_amdgcn_mfma_f32_16x16x32_bf16(ah, w, G[f], 0, 0, 0);
                G[f] = __builtin_amdgcn_mfma_f32_16x16x32_bf16(al, w, G[f], 0, 0, 0);
            }
            __builtin_amdgcn_s_setprio(0);
        }
        #pragma unroll
        for (int f = 0; f < 4; f++) {
            float bv = biasf[g * 128 + ncol0 + f * 16 + a16];
            #pragma unroll
            for (int j = 0; j < 4; j++) G[f][j] += bv;
        }
    };

    // hn: A rows = rh from tbR (buf1, XOR-swizzled), W from buf0
    auto gemmL = [&](int g) {
        #pragma unroll
        for (int f = 0; f < 4; f++) G[f] = zv;
        const unsigned short* wb = wbuf[0];
        #pragma unroll
        for (int c = 0; c < 4; c++) {
            const int rk = (c * 32 + agrp * 8) ^ rswA;
            f32x4 x0 = *(const f32x4*)(&tbR[locrow_a * 128 + rk]);
            f32x4 x1 = *(const f32x4*)(&tbR[locrow_a * 128 + rk + 4]);
            bf16x8 ah, al;
            splitc2(x0, x1, ah, al);
            __builtin_amdgcn_s_setprio(1);
            #pragma unroll
            for (int f = 0; f < 4; f++) {
                const int fglob = colgrp * 4 + f;
                const bf16x8 w = *(const bf16x8*)(&wb[(size_t)(c * 8 + fglob) * 512 + lane * 8]);
                G[f] = __builtin_amdgcn_mfma_f32_16x16x32_bf16(ah, w, G[f], 0, 0, 0);
                G[f] = __builtin_amdgcn_mfma_f32_16x16x32_bf16(al, w, G[f], 0, 0, 0);
            }
            __builtin_amdgcn_s_setprio(0);
        }
        #pragma unroll
        for (int f = 0; f < 4; f++) {
            float bv = biasf[g * 128 + ncol0 + f * 16 + a16];
            #pragma unroll
            for (int j = 0; j < 4; j++) G[f][j] += bv;
        }
    };

    auto sigm = [](float x) { return 1.f / (1.f + __expf(-x)); };
    auto tanh_ = [](float x) {
        x = fminf(18.f, fmaxf(-18.f, x));
        float e = __expf(2.f * x);
        return (e - 1.f) / (e + 1.f);
    };

    const unsigned long long GT = 0x417528306ULL;  // nibble u -> gemm id
    const unsigned CBT = 0x152u;                   // bit u -> compute buffer
    stageu(6, 0);                                  // prologue: W_hr -> buf0

    #pragma clang loop unroll(disable)
    for (int u = 0; u < 9; ++u) {
        const int g = (int)((GT >> (4 * u)) & 15);
        __syncthreads();               // drains W(g) stage; prior readers done
        if (u == 3) {
            gemmL(g);                  // A = rh (buf1), W = buf0
        } else {
            if (u != 2 && u != 8)      // prefetch next gemm's W
                stageu((int)((GT >> (4 * (u + 1))) & 15), (CBT >> (u + 1)) & 1);
            const float* pA = (u == 0 || u == 6) ? pAhid
                            : (u == 1 || u == 4 || u == 7) ? pAin : pAseq;
            gemmG((CBT >> u) & 1, pA, g);
        }
        // ---- merge G into persistent state ----
        switch (u) {
            case 0: case 6:
                #pragma unroll
                for (int f = 0; f < 4; f++) hx[f] = G[f];
                break;
            case 1: case 7:
                #pragma unroll
                for (int f = 0; f < 4; f++)
                    #pragma unroll
                    for (int j = 0; j < 4; j++)
                        s1[f][j] = sigm(G[f][j] + hx[f][j]);
                break;
            case 2: {                  // r = 0.5(s1 + sigm(G+hx)); rh -> buf1
                #pragma unroll
                for (int f = 0; f < 4; f++)
                    #pragma unroll
                    for (int j = 0; j < 4; j++) {
                        int row = rowgrp * 16 + agrp * 4 + j;
                        int col = ncol0 + f * 16 + a16;
                        float r = 0.5f * (s1[f][j] + sigm(G[f][j] + hx[f][j]));
                        float h = hid[(row0 + row) * 128 + col];
                        tbR[row * 128 + (col ^ ((row & 7) << 3))] = r * h;
                    }
                break;
            }
            case 3:
                #pragma unroll
                for (int f = 0; f < 4; f++) nacc[f] = G[f];
                break;
            case 4: case 5:
                #pragma unroll
                for (int f = 0; f < 4; f++) nacc[f] += G[f];
                break;
            default:                   // u == 8: G holds sz result
                break;
        }
        if (u == 2) { __syncthreads(); stageu(8, 0); }  // rh published; W_hn
        if (u == 3) { __syncthreads(); stageu(2, 1); }  // rh readers done; W_in
    }

    // ---- blend: z = 0.5(s1 + sigm(G+hx)); out = (1-z)tanh(nacc) + z*h ----
    // buf0's last readers were u7 (all passed u8's top barrier) -> safe now.
    #pragma unroll
    for (int f = 0; f < 4; f++)
        #pragma unroll
        for (int j = 0; j < 4; j++) {
            int row = rowgrp * 16 + agrp * 4 + j;
            int col = ncol0 + f * 16 + a16;
            float zz = 0.5f * (s1[f][j] + sigm(G[f][j] + hx[f][j]));
            float h  = hid[(row0 + row) * 128 + col];
            float nn = tanh_(nacc[f][j]);
            tbO[row * 128 + (col ^ ((row & 7) << 3))] = (1.f - zz) * nn + zz * h;
        }
    __syncthreads();
    #pragma unroll
    for (int p = 0; p < 4; p++) {
        int e = p * 2048 + tid * 4;
        int rrow = e >> 7, c0 = e & 127;
        f32x4 v = *(const f32x4*)(&tbO[rrow * 128 + (c0 ^ ((rrow & 7) << 3))]);
        *(f32x4*)(&outp[(row0 + rrow) * 128 + c0]) = v;
    }
}

extern "C" void kernel_launch(void* const* d_in, const int* in_sizes, int n_in,
                              void* d_out, int out_size, void* d_ws, size_t ws_size,
                              hipStream_t stream)
{
    (void)in_sizes; (void)n_in; (void)out_size; (void)ws_size;
    const float* inp  = (const float*)d_in[0];
    const float* seqp = (const float*)d_in[1];
    const float* hid  = (const float*)d_in[2];
    const float* W[9]; const float* Bv[9];
    for (int i = 0; i < 9; i++) {
        W[i]  = (const float*)d_in[3 + 2 * i];
        Bv[i] = (const float*)d_in[4 + 2 * i];
    }
    unsigned short* wp = (unsigned short*)d_ws; // needs 294,912 + 4,608 B

    pack_weights<<<9, PACK_BDIM, 0, stream>>>(W[0], W[1], W[2], W[3], W[4],
                                              W[5], W[6], W[7], W[8],
                                              Bv[0], Bv[1], Bv[2], Bv[3], Bv[4],
                                              Bv[5], Bv[6], Bv[7], Bv[8], wp);
    gru_fused<<<2048, BDIM, 0, stream>>>(inp, seqp, hid, wp, (float*)d_out);
}